// Round 7
// baseline (479.383 us; speedup 1.0000x reference)
//
#include <hip/hip_runtime.h>
#include <hip/hip_bf16.h>
#include <hip/hip_cooperative_groups.h>

#define KDIM 1000
#define KPAD 1024
#define DDIM 2048
#define BDIM 8192
#define TINV 0.25f   // 1/T, T=4
#define KSPLIT 4     // gram K-split factor

namespace cg = cooperative_groups;

typedef __attribute__((ext_vector_type(8))) short bf16x8;
typedef __attribute__((ext_vector_type(4))) float f32x4;
typedef __attribute__((ext_vector_type(4))) unsigned short u16x4;

__device__ inline float wred_sum(float v){
  #pragma unroll
  for (int m = 32; m; m >>= 1) v += __shfl_xor(v, m, 64);
  return v;
}
__device__ inline unsigned short f2bf_rne(float f){
  unsigned u = __float_as_uint(f);
  return (unsigned short)((u + 0x7FFFu + ((u >> 16) & 1u)) >> 16);
}
__device__ inline float bf2f(unsigned short h){
  return __uint_as_float(((unsigned)h) << 16);
}

// ws layout (bytes):
//   [128]                : unsigned int counter (for k_loss tail)
//   [256 .. )            : Wb bf16 [KPAD][DDIM]           (4 MB)
//   [+4MB .. )           : Gp f32 [KSPLIT][KPAD][KPAD]    (16 MB)
//   [+20MB .. )          : TSb bf16 [KDIM][KPAD]          (2 MB)
//   [+22MB .. )          : partials f32 [BDIM]            (32 KB)

// Kernel A (cooperative, grid 1024 x 256): convert -> gram -> ts.
// 1024 blocks @ <=128 VGPR -> 4 blocks/CU co-resident (256 CUs).
__global__ __launch_bounds__(256, 4) void k_fused(const float* __restrict__ W,
                                                  short* __restrict__ Wb,
                                                  float* __restrict__ Gp,
                                                  unsigned short* __restrict__ TSb,
                                                  unsigned int* __restrict__ counter){
  int bid = blockIdx.x, tid = threadIdx.x;
  int lane = tid & 63, w = tid >> 6;

  // ---- Phase 1: f32 -> bf16 convert (rows >= KDIM zeroed); zero tail counter.
  if (bid == 0 && tid == 0) *counter = 0u;
  {
    int base = (bid * 256 + tid) * 8;     // covers KPAD*DDIM exactly
    int row  = base >> 11;
    bf16x8 v;
    if (row < KDIM) {
      const float* src = W + base;
      #pragma unroll
      for (int i = 0; i < 8; i++) v[i] = (short)f2bf_rne(src[i]);
    } else {
      #pragma unroll
      for (int i = 0; i < 8; i++) v[i] = 0;
    }
    *(bf16x8*)(Wb + base) = v;
  }
  cg::this_grid().sync();

  // ---- Phase 2: Gp[z] = Wb[:, z*512:(z+1)*512] * (same)^T
  {
    int bx = bid & 15, by = (bid >> 4) & 15, z = bid >> 8;
    int i0 = bx * 64 + (w >> 1) * 32;
    int j0 = by * 64 + (w & 1) * 32;
    int r  = lane & 15, kb = (lane >> 4) * 8;
    const int K0 = z * (DDIM / KSPLIT);
    const short* pa = Wb + (size_t)(i0 + r) * DDIM + K0 + kb;
    const short* pb = Wb + (size_t)(j0 + r) * DDIM + K0 + kb;
    f32x4 c00 = {0,0,0,0}, c01 = {0,0,0,0}, c10 = {0,0,0,0}, c11 = {0,0,0,0};
    #pragma unroll 4
    for (int d = 0; d < DDIM / KSPLIT; d += 32){
      bf16x8 a0 = *(const bf16x8*)(pa + d);
      bf16x8 a1 = *(const bf16x8*)(pa + 16 * DDIM + d);
      bf16x8 b0 = *(const bf16x8*)(pb + d);
      bf16x8 b1 = *(const bf16x8*)(pb + 16 * DDIM + d);
      c00 = __builtin_amdgcn_mfma_f32_16x16x32_bf16(a0, b0, c00, 0, 0, 0);
      c01 = __builtin_amdgcn_mfma_f32_16x16x32_bf16(a0, b1, c01, 0, 0, 0);
      c10 = __builtin_amdgcn_mfma_f32_16x16x32_bf16(a1, b0, c10, 0, 0, 0);
      c11 = __builtin_amdgcn_mfma_f32_16x16x32_bf16(a1, b1, c11, 0, 0, 0);
    }
    // D layout: col = lane&15, row = (lane>>4)*4 + reg   [measured m89]
    int orow = (lane >> 4) * 4, ocol = lane & 15;
    float* g = Gp + ((size_t)z << 20) + (size_t)(i0 + orow) * KPAD + (j0 + ocol);
    #pragma unroll
    for (int rr = 0; rr < 4; rr++){
      g[(size_t)rr * KPAD]             = c00[rr];
      g[(size_t)rr * KPAD + 16]        = c01[rr];
      g[(size_t)(rr + 16) * KPAD]      = c10[rr];
      g[(size_t)(rr + 16) * KPAD + 16] = c11[rr];
    }
  }
  cg::this_grid().sync();

  // ---- Phase 3: TSb[l,:] = bf16(softmax(relu(sum_z Gp[z][l,:])^0.3 / 0.3))
  // (no max pass: logits <= ~34 -> exp <= 3.5e14, safe in f32)
  if (bid < KDIM){
    int l = bid;
    const f32x4* r0 = (const f32x4*)(Gp + (size_t)l * KPAD);
    const f32x4* r1 = (const f32x4*)(Gp + (1ull << 20) + (size_t)l * KPAD);
    const f32x4* r2 = (const f32x4*)(Gp + (2ull << 20) + (size_t)l * KPAD);
    const f32x4* r3 = (const f32x4*)(Gp + (3ull << 20) + (size_t)l * KPAD);
    f32x4 g = r0[tid] + r1[tid] + r2[tid] + r3[tid];
    f32x4 e;
    float s = 0.f;
    #pragma unroll
    for (int c = 0; c < 4; c++){
      int k = tid * 4 + c;
      float gg = g[c];
      float z  = (gg > 0.f) ? __expf(0.3f * __logf(gg)) * (1.0f / 0.3f) : 0.f;
      float ee = (k < KDIM) ? __expf(z) : 0.f;
      e[c] = ee;
      s += ee;
    }
    s = wred_sum(s);
    __shared__ float ps[4];
    if (lane == 0) ps[w] = s;
    __syncthreads();
    float inv = 1.0f / (ps[0] + ps[1] + ps[2] + ps[3]);
    u16x4 o;
    #pragma unroll
    for (int c = 0; c < 4; c++) o[c] = f2bf_rne(e[c] * inv);
    *(u16x4*)(TSb + (size_t)l * KPAD + tid * 4) = o;
  }
}

// Kernel B: per-row loss (one wave per batch row) + last-block reduction tail.
__global__ __launch_bounds__(256) void k_loss(const float* __restrict__ pred,
                                              const float* __restrict__ teacher,
                                              const int* __restrict__ label,
                                              const unsigned short* __restrict__ TSb,
                                              float* __restrict__ partials,
                                              unsigned int* __restrict__ counter,
                                              float* __restrict__ out){
  int lane = threadIdx.x & 63, w = threadIdx.x >> 6;
  int b = blockIdx.x * 4 + w;
  int l = label[b];
  const f32x4*  pr  = (const f32x4*)(pred    + (size_t)b * KDIM);
  const f32x4*  th  = (const f32x4*)(teacher + (size_t)b * KDIM);
  const u16x4*  tsr = (const u16x4*)(TSb + (size_t)l * KPAD);
  f32x4 x[4], y[4];
  u16x4 ts[4];
  #pragma unroll
  for (int j = 0; j < 4; j++){
    int i4 = lane + 64 * j;
    bool v = (i4 < 250);               // i4 < 250 <=> k < 1000
    f32x4 neg = {-4e30f, -4e30f, -4e30f, -4e30f};
    f32x4 p  = v ? pr[i4]  : neg;
    f32x4 t  = v ? th[i4]  : neg;
    ts[j]    = v ? tsr[i4] : (u16x4){0,0,0,0};
    x[j] = p * TINV;
    y[j] = t * TINV;
  }
  float sp = 0.f, st = 0.f;
  #pragma unroll
  for (int j = 0; j < 4; j++)
    #pragma unroll
    for (int c = 0; c < 4; c++){
      sp += __expf(x[j][c]);           // sentinel lanes: exp(-4e30)=0
      st += __expf(y[j][c]);
    }
  sp = wred_sum(sp); st = wred_sum(st);
  float lse_p = __logf(sp);
  float lse_t = __logf(st);
  // teacher logit at k=l, from registers: k = 4*lane + 256*j + c
  int jl = l >> 8, cl = l & 3, lanel = (l >> 2) & 63;
  f32x4 yj   = (jl == 0) ? y[0] : (jl == 1) ? y[1] : (jl == 2) ? y[2] : y[3];
  float cand = (cl == 0) ? yj[0] : (cl == 1) ? yj[1] : (cl == 2) ? yj[2] : yj[3];
  float yl   = __shfl(cand, lanel, 64);
  float conf = __expf(yl - lse_t);
  float u = (1.f - conf) * (1.f / 999.f);
  float S = 0.f;
  #pragma unroll
  for (int j = 0; j < 4; j++){
    int i4 = lane + 64 * j;
    if (i4 < 250){
      #pragma unroll
      for (int c = 0; c < 4; c++){
        int k = i4 * 4 + c;
        float t = 0.5f * (((k == l) ? conf : u) + bf2f(ts[j][c]));
        S += t * (__logf(t) - x[j][c]);
      }
    }
  }
  S = wred_sum(S);
  if (lane == 0) partials[b] = S + lse_p;   // sum(target)=1 -> + lse_p

  // ---- last-block-done reduction tail ----
  __threadfence();                     // publish partials at agent scope
  __syncthreads();
  __shared__ bool amLast;
  if (threadIdx.x == 0){
    unsigned old = __hip_atomic_fetch_add(counter, 1u, __ATOMIC_ACQ_REL,
                                          __HIP_MEMORY_SCOPE_AGENT);
    amLast = (old == (unsigned)(BDIM / 4 - 1));
  }
  __syncthreads();
  if (amLast){
    int t = threadIdx.x;
    float s = 0.f;
    #pragma unroll 8
    for (int i = t; i < BDIM; i += 256)
      s += __hip_atomic_load(&partials[i], __ATOMIC_RELAXED,
                             __HIP_MEMORY_SCOPE_AGENT);  // bypass stale XCD L2
    s = wred_sum(s);
    __shared__ float ps2[4];
    if ((t & 63) == 0) ps2[t >> 6] = s;
    __syncthreads();
    if (t == 0) out[0] = (ps2[0] + ps2[1] + ps2[2] + ps2[3]) * (16.0f / 8192.0f);
  }
}

extern "C" void kernel_launch(void* const* d_in, const int* in_sizes, int n_in,
                              void* d_out, int out_size, void* d_ws, size_t ws_size,
                              hipStream_t stream) {
  const float* pred    = (const float*)d_in[0];
  const float* teacher = (const float*)d_in[1];
  const float* weight  = (const float*)d_in[2];
  const int*   label   = (const int*)d_in[3];
  float* out = (float*)d_out;

  char* ws = (char*)d_ws;
  unsigned int*   counter  = (unsigned int*)(ws + 128);
  short*          Wb       = (short*)(ws + 256);
  float*          Gp       = (float*)(ws + 256 + (size_t)KPAD * DDIM * 2);
  unsigned short* TSb      = (unsigned short*)(ws + 256 + (size_t)KPAD * DDIM * 2
                                                  + (size_t)KSPLIT * KPAD * KPAD * 4);
  float*          partials = (float*)((char*)TSb + (size_t)KDIM * KPAD * 2);

  void* argsA[] = {(void*)&weight, (void*)&Wb, (void*)&Gp, (void*)&TSb, (void*)&counter};
  hipLaunchCooperativeKernel((const void*)k_fused, dim3(1024), dim3(256),
                             argsA, 0, stream);
  k_loss<<<dim3(BDIM / 4), dim3(256), 0, stream>>>(pred, teacher, label, TSb,
                                                   partials, counter, out);
}

// Round 8
// 65.140 us; speedup vs baseline: 7.3592x; 7.3592x over previous
//
#include <hip/hip_runtime.h>
#include <hip/hip_bf16.h>

#define KDIM 1000
#define KPAD 1024
#define DDIM 2048
#define BDIM 8192
#define TINV 0.25f   // 1/T, T=4
#define KSPLIT 4     // k_gram K-split factor

typedef __attribute__((ext_vector_type(8))) short bf16x8;
typedef __attribute__((ext_vector_type(4))) float f32x4;
typedef __attribute__((ext_vector_type(4))) unsigned short u16x4;

__device__ inline float wred_sum(float v){
  #pragma unroll
  for (int m = 32; m; m >>= 1) v += __shfl_xor(v, m, 64);
  return v;
}
__device__ inline unsigned short f2bf_rne(float f){
  unsigned u = __float_as_uint(f);
  return (unsigned short)((u + 0x7FFFu + ((u >> 16) & 1u)) >> 16);
}
__device__ inline float bf2f(unsigned short h){
  return __uint_as_float(((unsigned)h) << 16);
}

// ws layout (bytes):
//   [256 .. )            : Wb bf16 [KPAD][DDIM]           (4 MB)
//   [+4MB .. )           : Gp f32 [KSPLIT][KPAD][KPAD]    (16 MB)
//   [+20MB .. )          : TSb bf16 [KDIM][KPAD]          (2 MB)
//   [+22MB .. )          : partials f32 [BDIM]            (32 KB)

// Kernel 1: f32 -> bf16 convert (rows >= KDIM zero-padded).
__global__ __launch_bounds__(256) void k_convert(const float* __restrict__ W,
                                                 short* __restrict__ Wb){
  int gid  = blockIdx.x * 256 + threadIdx.x;
  int base = gid * 8;                // element index, row stride DDIM=2048
  int row  = base >> 11;
  bf16x8 v;
  if (row < KDIM) {
    const float* src = W + base;
    #pragma unroll
    for (int i = 0; i < 8; i++) v[i] = (short)f2bf_rne(src[i]);
  } else {
    #pragma unroll
    for (int i = 0; i < 8; i++) v[i] = 0;
  }
  *(bf16x8*)(Wb + base) = v;
}

// Kernel 2: Gp[z] = Wb[:, z*512:(z+1)*512] * (same)^T. Grid (16,16,4), 256 thr.
__global__ __launch_bounds__(256) void k_gram(const short* __restrict__ Wb,
                                              float* __restrict__ Gp){
  int lane = threadIdx.x & 63, w = threadIdx.x >> 6;
  int i0 = blockIdx.x * 64 + (w >> 1) * 32;
  int j0 = blockIdx.y * 64 + (w & 1) * 32;
  int z  = blockIdx.z;
  int r  = lane & 15, kb = (lane >> 4) * 8;
  const int K0 = z * (DDIM / KSPLIT);
  const short* pa = Wb + (size_t)(i0 + r) * DDIM + K0 + kb;
  const short* pb = Wb + (size_t)(j0 + r) * DDIM + K0 + kb;
  f32x4 c00 = {0,0,0,0}, c01 = {0,0,0,0}, c10 = {0,0,0,0}, c11 = {0,0,0,0};
  #pragma unroll 4
  for (int d = 0; d < DDIM / KSPLIT; d += 32){
    bf16x8 a0 = *(const bf16x8*)(pa + d);
    bf16x8 a1 = *(const bf16x8*)(pa + 16 * DDIM + d);
    bf16x8 b0 = *(const bf16x8*)(pb + d);
    bf16x8 b1 = *(const bf16x8*)(pb + 16 * DDIM + d);
    c00 = __builtin_amdgcn_mfma_f32_16x16x32_bf16(a0, b0, c00, 0, 0, 0);
    c01 = __builtin_amdgcn_mfma_f32_16x16x32_bf16(a0, b1, c01, 0, 0, 0);
    c10 = __builtin_amdgcn_mfma_f32_16x16x32_bf16(a1, b0, c10, 0, 0, 0);
    c11 = __builtin_amdgcn_mfma_f32_16x16x32_bf16(a1, b1, c11, 0, 0, 0);
  }
  // D layout: col = lane&15, row = (lane>>4)*4 + reg   [measured m89]
  int orow = (lane >> 4) * 4, ocol = lane & 15;
  float* g = Gp + ((size_t)z << 20) + (size_t)(i0 + orow) * KPAD + (j0 + ocol);
  #pragma unroll
  for (int rr = 0; rr < 4; rr++){
    g[(size_t)rr * KPAD]             = c00[rr];
    g[(size_t)rr * KPAD + 16]        = c01[rr];
    g[(size_t)(rr + 16) * KPAD]      = c10[rr];
    g[(size_t)(rr + 16) * KPAD + 16] = c11[rr];
  }
}

// Kernel 3: TSb[l,:] = bf16(softmax(relu(sum_z Gp[z][l,:])^0.3 / 0.3)).
// One block (256 thr) per row; no max pass (logits <= ~34, exp safe in f32).
__global__ __launch_bounds__(256) void k_ts(const float* __restrict__ Gp,
                                            unsigned short* __restrict__ TSb){
  int l = blockIdx.x;                 // 0..999
  int t = threadIdx.x;                // i4 index 0..255
  int lane = t & 63, w = t >> 6;
  const f32x4* r0 = (const f32x4*)(Gp + (size_t)l * KPAD);
  const f32x4* r1 = (const f32x4*)(Gp + (1ull << 20) + (size_t)l * KPAD);
  const f32x4* r2 = (const f32x4*)(Gp + (2ull << 20) + (size_t)l * KPAD);
  const f32x4* r3 = (const f32x4*)(Gp + (3ull << 20) + (size_t)l * KPAD);
  f32x4 g = r0[t] + r1[t] + r2[t] + r3[t];
  f32x4 e;
  float s = 0.f;
  #pragma unroll
  for (int c = 0; c < 4; c++){
    int k = t * 4 + c;
    float gg = g[c];
    float z  = (gg > 0.f) ? __expf(0.3f * __logf(gg)) * (1.0f / 0.3f) : 0.f;
    float ee = (k < KDIM) ? __expf(z) : 0.f;   // z in [0,~34] -> exp <= 3.5e14
    e[c] = ee;
    s += ee;
  }
  s = wred_sum(s);
  __shared__ float ps[4];
  if (lane == 0) ps[w] = s;
  __syncthreads();
  float inv = 1.0f / (ps[0] + ps[1] + ps[2] + ps[3]);
  u16x4 o;
  #pragma unroll
  for (int c = 0; c < 4; c++) o[c] = f2bf_rne(e[c] * inv);
  *(u16x4*)(TSb + (size_t)l * KPAD + t * 4) = o;
}

// Kernel 4: per-row loss, 2 WAVES PER ROW (half-row each), LDS combine.
// Grid 4096 blocks x 256 thr: block = 2 rows x 2 waves.
// Half h covers f32x4 indices [h*125, h*125+125) (500 floats each).
__global__ __launch_bounds__(256) void k_loss(const float* __restrict__ pred,
                                              const float* __restrict__ teacher,
                                              const int* __restrict__ label,
                                              const unsigned short* __restrict__ TSb,
                                              float* __restrict__ partials){
  int tid = threadIdx.x;
  int lane = tid & 63;
  int wv   = tid >> 6;            // 0..3
  int rib  = wv >> 1;             // row in block: 0,1
  int h    = wv & 1;              // half: 0,1
  int b = blockIdx.x * 2 + rib;
  int l = label[b];
  const int base4 = h * 125;
  const u16x4* tsr = (const u16x4*)(TSb + (size_t)l * KPAD) + base4;
  const f32x4* pr  = (const f32x4*)(pred    + (size_t)b * KDIM) + base4;
  const f32x4* th  = (const f32x4*)(teacher + (size_t)b * KDIM) + base4;

  u16x4 ts[2];
  f32x4 x[2], y[2];
  #pragma unroll
  for (int j = 0; j < 2; j++){
    int idx = lane + 64 * j;           // 0..127, valid < 125
    bool v = (idx < 125);
    f32x4 neg = {-4e30f, -4e30f, -4e30f, -4e30f};
    ts[j]   = v ? tsr[idx] : (u16x4){0,0,0,0};
    f32x4 p = v ? pr[idx]  : neg;
    f32x4 t = v ? th[idx]  : neg;
    x[j] = p * TINV;
    y[j] = t * TINV;
  }
  float sp = 0.f, st = 0.f;
  #pragma unroll
  for (int j = 0; j < 2; j++)
    #pragma unroll
    for (int c = 0; c < 4; c++){
      sp += __expf(x[j][c]);           // sentinel lanes: exp(-4e30)=0
      st += __expf(y[j][c]);
    }
  sp = wred_sum(sp); st = wred_sum(st);

  __shared__ float s_sp[4], s_st[4], s_yl[2], s_S[4];
  if (lane == 0){ s_sp[wv] = sp; s_st[wv] = st; }
  // teacher logit at k=l if it lives in this half: l4 = l>>2 in [base4, base4+125)
  int l4 = l >> 2;
  if (l4 >= base4 && l4 < base4 + 125){
    int rel = l4 - base4;
    int jl = rel >> 6, lanel = rel & 63, cl = l & 3;
    f32x4 yj   = jl ? y[1] : y[0];
    float cand = (cl == 0) ? yj[0] : (cl == 1) ? yj[1] : (cl == 2) ? yj[2] : yj[3];
    float yl   = __shfl(cand, lanel, 64);
    if (lane == 0) s_yl[rib] = yl;
  }
  __syncthreads();
  float spF = s_sp[rib * 2] + s_sp[rib * 2 + 1];
  float stF = s_st[rib * 2] + s_st[rib * 2 + 1];
  float lse_p = __logf(spF);
  float lse_t = __logf(stF);
  float conf  = __expf(s_yl[rib] - lse_t);
  float u = (1.f - conf) * (1.f / 999.f);

  float S = 0.f;
  #pragma unroll
  for (int j = 0; j < 2; j++){
    int idx = lane + 64 * j;
    if (idx < 125){
      #pragma unroll
      for (int c = 0; c < 4; c++){
        int k = (base4 + idx) * 4 + c;
        float t = 0.5f * (((k == l) ? conf : u) + bf2f(ts[j][c]));
        S += t * (__logf(t) - x[j][c]);
      }
    }
  }
  S = wred_sum(S);
  if (lane == 0) s_S[wv] = S;
  __syncthreads();
  if (h == 0 && lane == 0)
    partials[b] = s_S[rib * 2] + s_S[rib * 2 + 1] + lse_p;  // sum(target)=1 -> +lse_p
}

// Kernel 5: reduce 8192 partials, scale. 1 block, 256 threads.
__global__ __launch_bounds__(256) void k_fin(const float* __restrict__ partials,
                                             float* __restrict__ out){
  int t = threadIdx.x;
  float s = 0.f;
  #pragma unroll 8
  for (int i = t; i < BDIM; i += 256) s += partials[i];
  s = wred_sum(s);
  __shared__ float ps[4];
  if ((t & 63) == 0) ps[t >> 6] = s;
  __syncthreads();
  if (t == 0) out[0] = (ps[0] + ps[1] + ps[2] + ps[3]) * (16.0f / 8192.0f);
}

extern "C" void kernel_launch(void* const* d_in, const int* in_sizes, int n_in,
                              void* d_out, int out_size, void* d_ws, size_t ws_size,
                              hipStream_t stream) {
  const float* pred    = (const float*)d_in[0];
  const float* teacher = (const float*)d_in[1];
  const float* weight  = (const float*)d_in[2];
  const int*   label   = (const int*)d_in[3];
  float* out = (float*)d_out;

  char* ws = (char*)d_ws;
  short*          Wb       = (short*)(ws + 256);
  float*          Gp       = (float*)(ws + 256 + (size_t)KPAD * DDIM * 2);
  unsigned short* TSb      = (unsigned short*)(ws + 256 + (size_t)KPAD * DDIM * 2
                                                  + (size_t)KSPLIT * KPAD * KPAD * 4);
  float*          partials = (float*)((char*)TSb + (size_t)KDIM * KPAD * 2);

  k_convert<<<dim3((KPAD * DDIM / 8) / 256), dim3(256), 0, stream>>>(weight, Wb);
  k_gram<<<dim3(KPAD / 64, KPAD / 64, KSPLIT), dim3(256), 0, stream>>>(Wb, Gp);
  k_ts<<<dim3(KDIM), dim3(256), 0, stream>>>(Gp, TSb);
  k_loss<<<dim3(BDIM / 2), dim3(256), 0, stream>>>(pred, teacher, label, TSb, partials);
  k_fin<<<dim3(1), dim3(256), 0, stream>>>(partials, out);
}